// Round 11
// baseline (162.804 us; speedup 1.0000x reference)
//
#include <hip/hip_runtime.h>
#include <hip/hip_bf16.h>
#include <math.h>

#define N_NODES 50000
#define N_PAD   50048    // 391 * 128
#define N_EDGES 500000
#define E_TOT   550000   // N_EDGES + N_NODES self loops
#define HC      256      // HEADS*OUT_C
#define NHC     512      // both projections
#define HEADS   4
#define NEG     0.2f

typedef __attribute__((ext_vector_type(8))) short short8;
typedef __attribute__((ext_vector_type(4))) float f32x4;
typedef __attribute__((ext_vector_type(2))) float f32x2;

// f32 -> bf16 bits, round-to-nearest-even (matches HW convert)
__device__ __forceinline__ ushort f2bf(float f) {
    union { float f; unsigned u; } c; c.f = f;
    unsigned u = c.u;
    unsigned rounded = u + 0x7FFFu + ((u >> 16) & 1u);
    return (ushort)(rounded >> 16);
}

// ---------------- workspace layout (bytes) ----------------
static constexpr size_t OFF_COUNTS = 0;                                   // 50000 int
static constexpr size_t OFF_CUR    = OFF_COUNTS + (size_t)N_NODES * 4;    // 50000 int
static constexpr size_t OFF_ROWS   = OFF_CUR + (size_t)N_NODES * 4;       // 50001 int
static constexpr size_t OFF_SRCS   = OFF_ROWS + (size_t)(N_NODES + 1) * 4;// 550000 int
static constexpr size_t OFF_BSUM   = OFF_SRCS + (size_t)E_TOT * 4;        // 64 int
static constexpr size_t OFF_MODE   = OFF_BSUM + 64 * 4;                   // 1 int
static constexpr size_t OFF_XB     = ((OFF_MODE + 4 + 255) / 256) * 256;  // 50048*256 bf16
static constexpr size_t OFF_WT     = OFF_XB + (size_t)N_PAD * HC * 2;     // 512*256 bf16
static constexpr size_t OFF_XLB    = OFF_WT + (size_t)NHC * HC * 2;       // 50000*256 bf16
static constexpr size_t OFF_XRB    = OFF_XLB + (size_t)N_NODES * HC * 2;  // 50000*256 bf16
// end ~80 MB

// ---------------- edge index accessors (int32 vs int64 storage) -------------
__device__ __forceinline__ int get_src(const int* __restrict__ ei, int mode, int e) {
    if (e >= N_EDGES) return e - N_EDGES;
    return mode ? ei[2 * e] : ei[e];
}
__device__ __forceinline__ int get_dst(const int* __restrict__ ei, int mode, int e) {
    if (e >= N_EDGES) return e - N_EDGES;
    return mode ? ei[2 * (N_EDGES + e)] : ei[N_EDGES + e];
}

// ---- fused prep: cvt_x | cvt_w | zero counts+cursor | detect (by block) ----
#define XBLK 6256   // ceil(50048*256/8 / 256)
#define WBLK 512    // 131072 / 256
#define ZBLK 98     // 25000 int4 / 256
__global__ __launch_bounds__(256) void prep_kernel(
        const float* __restrict__ x, const float* __restrict__ Wl,
        const float* __restrict__ Wr, const int* __restrict__ ei,
        ushort* __restrict__ xb, ushort* __restrict__ wt,
        int* __restrict__ cz, int* __restrict__ mode) {
    const int b = blockIdx.x;
    if (b < XBLK) {
        size_t i = ((size_t)b * 256 + threadIdx.x) * 8;
        if (i >= (size_t)N_PAD * HC) return;
        ushort o[8];
        if (i < (size_t)N_NODES * HC) {
            float4 v0 = *(const float4*)(x + i);
            float4 v1 = *(const float4*)(x + i + 4);
            o[0] = f2bf(v0.x); o[1] = f2bf(v0.y); o[2] = f2bf(v0.z); o[3] = f2bf(v0.w);
            o[4] = f2bf(v1.x); o[5] = f2bf(v1.y); o[6] = f2bf(v1.z); o[7] = f2bf(v1.w);
        } else {
#pragma unroll
            for (int j = 0; j < 8; ++j) o[j] = 0;
        }
        *(short8*)(xb + i) = *(short8*)o;
    } else if (b < XBLK + WBLK) {
        int i = (b - XBLK) * 256 + threadIdx.x;
        int n = i >> 8, k = i & 255;
        float v = (n < HC) ? Wl[(size_t)k * HC + n] : Wr[(size_t)k * HC + (n - HC)];
        wt[i] = f2bf(v);
    } else if (b < XBLK + WBLK + ZBLK) {
        int i4 = (b - XBLK - WBLK) * 256 + threadIdx.x;   // int4 index
        if (i4 < 2 * N_NODES / 4) *(int4*)(cz + i4 * 4) = make_int4(0, 0, 0, 0);
    } else {
        __shared__ int any;
        if (threadIdx.x == 0) any = 0;
        __syncthreads();
        if (ei[2 * threadIdx.x + 1] != 0) atomicOr(&any, 1);
        __syncthreads();
        if (threadIdx.x == 0) mode[0] = (any == 0) ? 1 : 0;  // 1 => int64
    }
}

// ------- MFMA GEMM [50048x256]x[256x512] -> xlb|xrb, plus count blocks ------
// Count blocks FIRST (short, drain early); gemm blocks single-buffer 16KB LDS
// (m99/m100: explicit dbuf is neutral — barrier vmcnt(0) drains prefetch anyway)
// -> ~7-8 blocks/CU residency instead of 5. Epilogue reuses the same 16KB in
// two 64-column passes with 16B-chunk XOR swizzle.
#define BM 128
#define BK 32
#define GEMM_BLKS 1564   // 391 * 4
#define CNT_BLKS  2149   // ceil(550000/256)
__global__ __launch_bounds__(256) void gemm_count_kernel(
        const __hip_bfloat16* __restrict__ xb, const __hip_bfloat16* __restrict__ wt,
        const float* __restrict__ bl, const float* __restrict__ br,
        ushort* __restrict__ xlb, ushort* __restrict__ xrb,
        const int* __restrict__ ei, const int* __restrict__ mode,
        int* __restrict__ counts) {
    __shared__ ushort smem[2 * BM * BK];                // 16 KB: As|Bs, reused by epilogue

    if (blockIdx.x < CNT_BLKS) {                        // ---- count blocks (first) ----
        int e = blockIdx.x * 256 + threadIdx.x;
        if (e < E_TOT) atomicAdd(&counts[get_dst(ei, *mode, e)], 1);
        return;
    }

    __hip_bfloat16* AS = (__hip_bfloat16*)smem;                 // 8 KB
    __hip_bfloat16* BS = (__hip_bfloat16*)(smem + BM * BK);     // 8 KB
    const int t    = threadIdx.x;
    const int lane = t & 63;
    const int wid  = t >> 6;
    const int wr   = wid >> 1, wc = wid & 1;
    const int gb   = blockIdx.x - CNT_BLKS;
    const int bx   = gb % 391, by = gb / 391;
    const int brow = bx * BM;
    const int bcol = by * BM;

    auto stage = [&](int k0) {
#pragma unroll
        for (int r = 0; r < 2; ++r) {
            int c = r * 256 + t;
            const __hip_bfloat16* ga = xb + ((size_t)(brow + (c >> 2)) * HC + k0 + (c & 3) * 8);
            __builtin_amdgcn_global_load_lds(
                (const __attribute__((address_space(1))) void*)ga,
                (__attribute__((address_space(3))) void*)((char*)AS + c * 16),
                16, 0, 0);
        }
#pragma unroll
        for (int r = 0; r < 2; ++r) {
            int c = r * 256 + t;
            const __hip_bfloat16* gb2 = wt + ((size_t)(bcol + (c >> 2)) * HC + k0 + (c & 3) * 8);
            __builtin_amdgcn_global_load_lds(
                (const __attribute__((address_space(1))) void*)gb2,
                (__attribute__((address_space(3))) void*)((char*)BS + c * 16),
                16, 0, 0);
        }
    };

    f32x4 acc[4][4];
#pragma unroll
    for (int m = 0; m < 4; ++m)
#pragma unroll
        for (int n = 0; n < 4; ++n) acc[m][n] = (f32x4)0.f;

    const int rsub = lane & 15;
    const int koff = (lane >> 4) * 16;

    for (int kk = 0; kk < 8; ++kk) {
        stage(kk * BK);
        __syncthreads();                 // compiler emits vmcnt(0) drain before barrier
        short8 a[4], b[4];
#pragma unroll
        for (int m = 0; m < 4; ++m)
            a[m] = *(const short8*)((const char*)AS +
                    (wr * 64 + m * 16 + rsub) * (BK * 2) + koff);
#pragma unroll
        for (int n = 0; n < 4; ++n)
            b[n] = *(const short8*)((const char*)BS +
                    (wc * 64 + n * 16 + rsub) * (BK * 2) + koff);
#pragma unroll
        for (int m = 0; m < 4; ++m)
#pragma unroll
            for (int n = 0; n < 4; ++n)
                acc[m][n] = __builtin_amdgcn_mfma_f32_16x16x32_bf16(a[m], b[n], acc[m][n], 0, 0, 0);
        __syncthreads();                 // protect LDS before next stage overwrites
    }

    // ---- epilogue: two 64-col passes through the 16KB buffer ----
    ushort* dst = (bcol < HC) ? xlb : xrb;
    const float* bvec = (bcol < HC) ? bl : br;
    const int cb = bcol & (HC - 1);
#pragma unroll
    for (int p = 0; p < 2; ++p) {
        if (wc == p) {
            // waves owning this column half write acc -> LDS (swizzled 16B chunks)
#pragma unroll
            for (int m = 0; m < 4; ++m) {
#pragma unroll
                for (int n = 0; n < 4; ++n) {
                    int c_h = n * 16 + rsub;            // 0..63 within half
                    float bv = bvec[cb + p * 64 + c_h];
#pragma unroll
                    for (int j = 0; j < 4; ++j) {
                        int r_loc = wr * 64 + m * 16 + (lane >> 4) * 4 + j;
                        smem[r_loc * 64 + (((c_h >> 3) ^ (r_loc & 7)) * 8) + (c_h & 7)] =
                            f2bf(acc[m][n][j] + bv);
                    }
                }
            }
        }
        __syncthreads();
        {
            const int r = t >> 1, sub = t & 1;          // 2 threads/row, 32 cols each
            if (brow + r < N_NODES) {
                ushort* gout = dst + (size_t)(brow + r) * HC + cb + p * 64 + sub * 32;
#pragma unroll
                for (int i = 0; i < 4; ++i) {
                    int ci = sub * 4 + i;
                    uint4 v = *(const uint4*)&smem[r * 64 + ((ci ^ (r & 7)) * 8)];
                    *(uint4*)(gout + i * 8) = v;
                }
            }
        }
        __syncthreads();
    }
}

// ---------------- CSR scan (2 kernels) --------------------------------------
__global__ void scan1_kernel(const int* __restrict__ counts, int* __restrict__ rows,
                             int* __restrict__ bsum) {
    __shared__ int sdata[256];
    const int t = threadIdx.x;
    const int base = blockIdx.x * 1024 + t * 4;
    int v[4]; int s = 0;
#pragma unroll
    for (int j = 0; j < 4; ++j) {
        int idx = base + j;
        v[j] = (idx < N_NODES) ? counts[idx] : 0;
        s += v[j];
    }
    sdata[t] = s;
    __syncthreads();
    for (int off = 1; off < 256; off <<= 1) {
        int xv = (t >= off) ? sdata[t - off] : 0;
        __syncthreads();
        sdata[t] += xv;
        __syncthreads();
    }
    int run = sdata[t] - s;
#pragma unroll
    for (int j = 0; j < 4; ++j) {
        int idx = base + j;
        if (idx < N_NODES) rows[idx] = run;
        run += v[j];
    }
    if (t == 255) bsum[blockIdx.x] = sdata[255];   // raw block total
}

// scan3': adds prefix of bsum (computed in-wave, no scan2 kernel needed)
__global__ void scan3_kernel(int* __restrict__ rows, const int* __restrict__ bsum) {
    const int idx = blockIdx.x * 256 + threadIdx.x;
    const int r = blockIdx.x >> 2;          // 1024-region, constant per block
    const int lane = threadIdx.x & 63;
    int v = (lane < r) ? bsum[lane] : 0;    // r <= 48 < 64
#pragma unroll
    for (int off = 1; off < 64; off <<= 1) v += __shfl_xor(v, off, 64);
    if (idx < N_NODES) rows[idx] += v;
    if (idx == 0) rows[N_NODES] = E_TOT;
}

// store SOURCE node id directly
__global__ void fill_kernel(const int* __restrict__ ei, const int* __restrict__ mode,
                            const int* __restrict__ rows, int* __restrict__ cursor,
                            int* __restrict__ srcs) {
    int e = blockIdx.x * blockDim.x + threadIdx.x;
    if (e < E_TOT) {
        int md = *mode;
        int d = get_dst(ei, md, e);
        int s = get_src(ei, md, e);
        int pos = atomicAdd(&cursor[d], 1);
        srcs[rows[d] + pos] = s;
    }
}

// ------- fused logits + softmax + aggregation: wave per node, 2 edges/wave --
// lanes 0-31 even edge slots, 32-63 odd; lane owns 8 channels as 4 float2 packs
// (pk_add/pk_max/pk_fma). 1-deep prefetch (R7-proven: TLP > ILP here).
// No online max: logits O(+-10), fp32 exp safe; normalization identical.
__global__ __launch_bounds__(256) void fused_agg_kernel(
        const ushort* __restrict__ xlb, const ushort* __restrict__ xrb,
        const float* __restrict__ att,
        const int* __restrict__ rows, const int* __restrict__ srcs,
        const float* __restrict__ bias, float* __restrict__ out) {
    const int lane = threadIdx.x & 63;
    const int n = (blockIdx.x * 256 + threadIdx.x) >> 6;
    if (n >= N_NODES) return;
    const int half = lane >> 5;       // edge-parity of this half-wave
    const int sl   = lane & 31;       // owns channels sl*8 .. sl*8+7
    const int start = rows[n], end = rows[n + 1];   // end > start (self loop)

    f32x2 xr2[4], at2[4];
    {
        uint4 c = *(const uint4*)(xrb + (size_t)n * HC + sl * 8);
        unsigned w[4] = {c.x, c.y, c.z, c.w};
#pragma unroll
        for (int j = 0; j < 4; ++j) {
            xr2[j][0] = __uint_as_float(w[j] << 16);
            xr2[j][1] = __uint_as_float(w[j] & 0xffff0000u);
        }
        float4 a0 = *(const float4*)&att[sl * 8];
        float4 a1 = *(const float4*)&att[sl * 8 + 4];
        at2[0][0] = a0.x; at2[0][1] = a0.y; at2[1][0] = a0.z; at2[1][1] = a0.w;
        at2[2][0] = a1.x; at2[2][1] = a1.y; at2[3][0] = a1.z; at2[3][1] = a1.w;
    }

    f32x2 acc2[4];
#pragma unroll
    for (int j = 0; j < 4; ++j) acc2[j] = (f32x2)0.f;
    float sm = 0.f;

    // 1-deep pipeline: next row in flight + next-next src id
    int i = start + half;
    uint4 rA = make_uint4(0, 0, 0, 0);
    int sB = -1;
    if (i < end) rA = *(const uint4*)(xlb + (size_t)srcs[i] * HC + sl * 8);
    if (i + 2 < end) sB = srcs[i + 2];

    for (; i < end; i += 2) {
        uint4 r = rA;
        if (sB >= 0) rA = *(const uint4*)(xlb + (size_t)sB * HC + sl * 8);
        sB = (i + 4 < end) ? srcs[i + 4] : -1;

        unsigned w[4] = {r.x, r.y, r.z, r.w};
        f32x2 xv[4];
#pragma unroll
        for (int j = 0; j < 4; ++j) {
            xv[j][0] = __uint_as_float(w[j] << 16);
            xv[j][1] = __uint_as_float(w[j] & 0xffff0000u);
        }

        f32x2 p2 = (f32x2)0.f;
#pragma unroll
        for (int j = 0; j < 4; ++j) {
            f32x2 v = xv[j] + xr2[j];                          // pk_add
            f32x2 lk = __builtin_elementwise_max(v, v * NEG);  // pk_mul + pk_max
            p2 = lk * at2[j] + p2;                             // pk_fma
        }
        float p = p2[0] + p2[1];
        p += __shfl_xor(p, 1, 64);
        p += __shfl_xor(p, 2, 64);
        p += __shfl_xor(p, 4, 64);

        float wgt = __expf(p);
        sm += wgt;
        f32x2 w2; w2[0] = wgt; w2[1] = wgt;
#pragma unroll
        for (int j = 0; j < 4; ++j) acc2[j] = xv[j] * w2 + acc2[j];  // pk_fma
    }

    // merge the two half-wave partials
    sm += __shfl_xor(sm, 32, 64);
#pragma unroll
    for (int j = 0; j < 4; ++j) {
        acc2[j][0] += __shfl_xor(acc2[j][0], 32, 64);
        acc2[j][1] += __shfl_xor(acc2[j][1], 32, 64);
    }

    if (half == 0) {
        const float inv = 1.0f / sm;
        float4 b0 = *(const float4*)&bias[sl * 8];
        float4 b1 = *(const float4*)&bias[sl * 8 + 4];
        float4 o0, o1;
        o0.x = fmaf(acc2[0][0], inv, b0.x); o0.y = fmaf(acc2[0][1], inv, b0.y);
        o0.z = fmaf(acc2[1][0], inv, b0.z); o0.w = fmaf(acc2[1][1], inv, b0.w);
        o1.x = fmaf(acc2[2][0], inv, b1.x); o1.y = fmaf(acc2[2][1], inv, b1.y);
        o1.z = fmaf(acc2[3][0], inv, b1.z); o1.w = fmaf(acc2[3][1], inv, b1.w);
        *(float4*)&out[(size_t)n * HC + sl * 8]     = o0;
        *(float4*)&out[(size_t)n * HC + sl * 8 + 4] = o1;
    }
}

// ---------------- host launcher ---------------------------------------------
extern "C" void kernel_launch(void* const* d_in, const int* in_sizes, int n_in,
                              void* d_out, int out_size, void* d_ws, size_t ws_size,
                              hipStream_t stream) {
    const float* x    = (const float*)d_in[0];
    const int*   ei   = (const int*)d_in[1];
    const float* Wl   = (const float*)d_in[2];
    const float* bl   = (const float*)d_in[3];
    const float* Wr   = (const float*)d_in[4];
    const float* br   = (const float*)d_in[5];
    const float* att  = (const float*)d_in[6];
    const float* bias = (const float*)d_in[7];
    float* out = (float*)d_out;

    char* ws = (char*)d_ws;
    int*   counts = (int*)(ws + OFF_COUNTS);
    int*   cursor = (int*)(ws + OFF_CUR);
    int*   rows   = (int*)(ws + OFF_ROWS);
    int*   srcs   = (int*)(ws + OFF_SRCS);
    int*   bsum   = (int*)(ws + OFF_BSUM);
    int*   mode   = (int*)(ws + OFF_MODE);
    ushort* xb    = (ushort*)(ws + OFF_XB);
    ushort* wt    = (ushort*)(ws + OFF_WT);
    ushort* xlb   = (ushort*)(ws + OFF_XLB);
    ushort* xrb   = (ushort*)(ws + OFF_XRB);

    // 1: fused cvt_x | cvt_w | zero(counts+cursor) | detect
    prep_kernel<<<XBLK + WBLK + ZBLK + 1, 256, 0, stream>>>(
        x, Wl, Wr, ei, xb, wt, counts, mode);

    // 2: count blocks first, then MFMA GEMM blocks
    gemm_count_kernel<<<CNT_BLKS + GEMM_BLKS, 256, 0, stream>>>(
        (const __hip_bfloat16*)xb, (const __hip_bfloat16*)wt, bl, br, xlb, xrb,
        ei, mode, counts);

    // 3-4: scan
    scan1_kernel<<<49, 256, 0, stream>>>(counts, rows, bsum);
    scan3_kernel<<<(N_NODES + 255) / 256, 256, 0, stream>>>(rows, bsum);

    // 5: fill CSR with src ids
    fill_kernel<<<(E_TOT + 255) / 256, 256, 0, stream>>>(ei, mode, rows, cursor, srcs);

    // 6: fused attention + aggregation
    fused_agg_kernel<<<(N_NODES + 3) / 4, 256, 0, stream>>>(
        xlb, xrb, att, rows, srcs, bias, out);
}

// Round 12
// 148.648 us; speedup vs baseline: 1.0952x; 1.0952x over previous
//
#include <hip/hip_runtime.h>
#include <hip/hip_bf16.h>
#include <math.h>

#define N_NODES 50000
#define N_PAD   50048    // 391 * 128
#define N_EDGES 500000
#define E_TOT   550000   // N_EDGES + N_NODES self loops
#define HC      256      // HEADS*OUT_C
#define NHC     512      // both projections
#define HEADS   4
#define NEG     0.2f

typedef __attribute__((ext_vector_type(8))) short short8;
typedef __attribute__((ext_vector_type(4))) float f32x4;
typedef __attribute__((ext_vector_type(2))) float f32x2;

// f32 -> bf16 bits, round-to-nearest-even (matches HW convert)
__device__ __forceinline__ ushort f2bf(float f) {
    union { float f; unsigned u; } c; c.f = f;
    unsigned u = c.u;
    unsigned rounded = u + 0x7FFFu + ((u >> 16) & 1u);
    return (ushort)(rounded >> 16);
}

// ---------------- workspace layout (bytes) ----------------
static constexpr size_t OFF_COUNTS = 0;                                   // 50000 int
static constexpr size_t OFF_CUR    = OFF_COUNTS + (size_t)N_NODES * 4;    // 50000 int
static constexpr size_t OFF_ROWS   = OFF_CUR + (size_t)N_NODES * 4;       // 50001 int
static constexpr size_t OFF_SRCS   = OFF_ROWS + (size_t)(N_NODES + 1) * 4;// 550000 int
static constexpr size_t OFF_BSUM   = OFF_SRCS + (size_t)E_TOT * 4;        // 64 int
static constexpr size_t OFF_MODE   = OFF_BSUM + 64 * 4;                   // 1 int
static constexpr size_t OFF_XB     = ((OFF_MODE + 4 + 255) / 256) * 256;  // 50048*256 bf16
static constexpr size_t OFF_WT     = OFF_XB + (size_t)N_PAD * HC * 2;     // 512*256 bf16
static constexpr size_t OFF_XLB    = OFF_WT + (size_t)NHC * HC * 2;       // 50000*256 bf16
static constexpr size_t OFF_XRB    = OFF_XLB + (size_t)N_NODES * HC * 2;  // 50000*256 bf16
// end ~80 MB

// ---------------- edge index accessors (int32 vs int64 storage) -------------
__device__ __forceinline__ int get_src(const int* __restrict__ ei, int mode, int e) {
    if (e >= N_EDGES) return e - N_EDGES;
    return mode ? ei[2 * e] : ei[e];
}
__device__ __forceinline__ int get_dst(const int* __restrict__ ei, int mode, int e) {
    if (e >= N_EDGES) return e - N_EDGES;
    return mode ? ei[2 * (N_EDGES + e)] : ei[N_EDGES + e];
}

// ---- fused prep: cvt_x | cvt_w | zero counts+cursor | detect (by block) ----
#define XBLK 6256   // ceil(50048*256/8 / 256)
#define WBLK 512    // 131072 / 256
#define ZBLK 98     // 25000 int4 / 256
__global__ __launch_bounds__(256) void prep_kernel(
        const float* __restrict__ x, const float* __restrict__ Wl,
        const float* __restrict__ Wr, const int* __restrict__ ei,
        ushort* __restrict__ xb, ushort* __restrict__ wt,
        int* __restrict__ cz, int* __restrict__ mode) {
    const int b = blockIdx.x;
    if (b < XBLK) {
        size_t i = ((size_t)b * 256 + threadIdx.x) * 8;
        if (i >= (size_t)N_PAD * HC) return;
        ushort o[8];
        if (i < (size_t)N_NODES * HC) {
            float4 v0 = *(const float4*)(x + i);
            float4 v1 = *(const float4*)(x + i + 4);
            o[0] = f2bf(v0.x); o[1] = f2bf(v0.y); o[2] = f2bf(v0.z); o[3] = f2bf(v0.w);
            o[4] = f2bf(v1.x); o[5] = f2bf(v1.y); o[6] = f2bf(v1.z); o[7] = f2bf(v1.w);
        } else {
#pragma unroll
            for (int j = 0; j < 8; ++j) o[j] = 0;
        }
        *(short8*)(xb + i) = *(short8*)o;
    } else if (b < XBLK + WBLK) {
        int i = (b - XBLK) * 256 + threadIdx.x;
        int n = i >> 8, k = i & 255;
        float v = (n < HC) ? Wl[(size_t)k * HC + n] : Wr[(size_t)k * HC + (n - HC)];
        wt[i] = f2bf(v);
    } else if (b < XBLK + WBLK + ZBLK) {
        int i4 = (b - XBLK - WBLK) * 256 + threadIdx.x;   // int4 index
        if (i4 < 2 * N_NODES / 4) *(int4*)(cz + i4 * 4) = make_int4(0, 0, 0, 0);
    } else {
        __shared__ int any;
        if (threadIdx.x == 0) any = 0;
        __syncthreads();
        if (ei[2 * threadIdx.x + 1] != 0) atomicOr(&any, 1);
        __syncthreads();
        if (threadIdx.x == 0) mode[0] = (any == 0) ? 1 : 0;  // 1 => int64
    }
}

// ------- MFMA GEMM [50048x256]x[256x512] -> xlb|xrb, plus count blocks ------
// R10-proven structure (dbuf 32KB, 72 VGPR). Single change: block->tile map
// with bijective XCD-chunk swizzle (nwg=1564=8*195+4) so the 4 column-blocks
// sharing an A-panel are consecutive works on the SAME XCD -> A-panel L2 reuse.
#define BM 128
#define BK 32
#define GEMM_BLKS 1564   // 391 * 4
#define CNT_BLKS  2149   // ceil(550000/256)
__global__ __launch_bounds__(256) void gemm_count_kernel(
        const __hip_bfloat16* __restrict__ xb, const __hip_bfloat16* __restrict__ wt,
        const float* __restrict__ bl, const float* __restrict__ br,
        ushort* __restrict__ xlb, ushort* __restrict__ xrb,
        const int* __restrict__ ei, const int* __restrict__ mode,
        int* __restrict__ counts) {
    __shared__ ushort smem[4 * BM * BK];                // 32 KB: As|Bs, reused by epilogue

    if (blockIdx.x >= GEMM_BLKS) {                      // ---- count blocks (tail) ----
        int e = (blockIdx.x - GEMM_BLKS) * 256 + threadIdx.x;
        if (e < E_TOT) atomicAdd(&counts[get_dst(ei, *mode, e)], 1);
        return;
    }

    auto AS = [&](int buf) { return (__hip_bfloat16*)(smem + buf * BM * BK); };
    auto BS = [&](int buf) { return (__hip_bfloat16*)(smem + 2 * BM * BK + buf * BM * BK); };
    const int t    = threadIdx.x;
    const int lane = t & 63;
    const int wid  = t >> 6;
    const int wr   = wid >> 1, wc = wid & 1;

    // bijective XCD-chunk swizzle (m204 form): origs with equal (orig&7) are
    // dispatched to the same XCD (round-robin); map them to a contiguous work
    // chunk. works 4k..4k+3 share bx (A-panel) and sit on one XCD.
    const int orig = blockIdx.x;
    const int xcd  = orig & 7;
    const int base = (xcd < 4) ? xcd * 196 : 784 + (xcd - 4) * 195;
    const int work = base + (orig >> 3);
    const int bx   = work >> 2, by = work & 3;
    const int brow = bx * BM;
    const int bcol = by * BM;

    auto stage = [&](int buf, int k0) {
#pragma unroll
        for (int r = 0; r < 2; ++r) {
            int c = r * 256 + t;
            const __hip_bfloat16* ga = xb + ((size_t)(brow + (c >> 2)) * HC + k0 + (c & 3) * 8);
            __builtin_amdgcn_global_load_lds(
                (const __attribute__((address_space(1))) void*)ga,
                (__attribute__((address_space(3))) void*)((char*)AS(buf) + c * 16),
                16, 0, 0);
        }
#pragma unroll
        for (int r = 0; r < 2; ++r) {
            int c = r * 256 + t;
            const __hip_bfloat16* gb2 = wt + ((size_t)(bcol + (c >> 2)) * HC + k0 + (c & 3) * 8);
            __builtin_amdgcn_global_load_lds(
                (const __attribute__((address_space(1))) void*)gb2,
                (__attribute__((address_space(3))) void*)((char*)BS(buf) + c * 16),
                16, 0, 0);
        }
    };

    f32x4 acc[4][4];
#pragma unroll
    for (int m = 0; m < 4; ++m)
#pragma unroll
        for (int n = 0; n < 4; ++n) acc[m][n] = (f32x4)0.f;

    stage(0, 0);
    __syncthreads();

    const int rsub = lane & 15;
    const int koff = (lane >> 4) * 16;

    for (int kk = 0; kk < 8; ++kk) {
        const int cur = kk & 1;
        if (kk < 7) stage(cur ^ 1, (kk + 1) * BK);
        short8 a[4], b[4];
#pragma unroll
        for (int m = 0; m < 4; ++m)
            a[m] = *(const short8*)((const char*)AS(cur) +
                    (wr * 64 + m * 16 + rsub) * (BK * 2) + koff);
#pragma unroll
        for (int n = 0; n < 4; ++n)
            b[n] = *(const short8*)((const char*)BS(cur) +
                    (wc * 64 + n * 16 + rsub) * (BK * 2) + koff);
#pragma unroll
        for (int m = 0; m < 4; ++m)
#pragma unroll
            for (int n = 0; n < 4; ++n)
                acc[m][n] = __builtin_amdgcn_mfma_f32_16x16x32_bf16(a[m], b[n], acc[m][n], 0, 0, 0);
        __syncthreads();
    }

    // ---- epilogue: acc -> LDS (16B-chunk XOR swizzle) -> coalesced stores ----
    ushort* dst = (bcol < HC) ? xlb : xrb;
    const float* bvec = (bcol < HC) ? bl : br;
    const int cb = bcol & (HC - 1);
#pragma unroll
    for (int m = 0; m < 4; ++m) {
#pragma unroll
        for (int n = 0; n < 4; ++n) {
            int c_loc = wc * 64 + n * 16 + (lane & 15);
            float bv = bvec[cb + c_loc];
#pragma unroll
            for (int j = 0; j < 4; ++j) {
                int r_loc = wr * 64 + m * 16 + (lane >> 4) * 4 + j;
                smem[r_loc * 128 + (((c_loc >> 3) ^ (r_loc & 15)) * 8) + (c_loc & 7)] =
                    f2bf(acc[m][n][j] + bv);
            }
        }
    }
    __syncthreads();
    {
        const int r = t >> 1, hf = t & 1;
        if (brow + r < N_NODES) {
            ushort* gout = dst + (size_t)(brow + r) * HC + cb + hf * 64;
#pragma unroll
            for (int i = 0; i < 8; ++i) {
                int ci = hf * 8 + i;
                uint4 v = *(const uint4*)&smem[r * 128 + ((ci ^ (r & 15)) * 8)];
                *(uint4*)(gout + i * 8) = v;
            }
        }
    }
}

// ---------------- CSR scan (2 kernels) --------------------------------------
__global__ void scan1_kernel(const int* __restrict__ counts, int* __restrict__ rows,
                             int* __restrict__ bsum) {
    __shared__ int sdata[256];
    const int t = threadIdx.x;
    const int base = blockIdx.x * 1024 + t * 4;
    int v[4]; int s = 0;
#pragma unroll
    for (int j = 0; j < 4; ++j) {
        int idx = base + j;
        v[j] = (idx < N_NODES) ? counts[idx] : 0;
        s += v[j];
    }
    sdata[t] = s;
    __syncthreads();
    for (int off = 1; off < 256; off <<= 1) {
        int xv = (t >= off) ? sdata[t - off] : 0;
        __syncthreads();
        sdata[t] += xv;
        __syncthreads();
    }
    int run = sdata[t] - s;
#pragma unroll
    for (int j = 0; j < 4; ++j) {
        int idx = base + j;
        if (idx < N_NODES) rows[idx] = run;
        run += v[j];
    }
    if (t == 255) bsum[blockIdx.x] = sdata[255];   // raw block total
}

// scan3': adds prefix of bsum (computed in-wave, no scan2 kernel needed)
__global__ void scan3_kernel(int* __restrict__ rows, const int* __restrict__ bsum) {
    const int idx = blockIdx.x * 256 + threadIdx.x;
    const int r = blockIdx.x >> 2;          // 1024-region, constant per block
    const int lane = threadIdx.x & 63;
    int v = (lane < r) ? bsum[lane] : 0;    // r <= 48 < 64
#pragma unroll
    for (int off = 1; off < 64; off <<= 1) v += __shfl_xor(v, off, 64);
    if (idx < N_NODES) rows[idx] += v;
    if (idx == 0) rows[N_NODES] = E_TOT;
}

// store SOURCE node id directly
__global__ void fill_kernel(const int* __restrict__ ei, const int* __restrict__ mode,
                            const int* __restrict__ rows, int* __restrict__ cursor,
                            int* __restrict__ srcs) {
    int e = blockIdx.x * blockDim.x + threadIdx.x;
    if (e < E_TOT) {
        int md = *mode;
        int d = get_dst(ei, md, e);
        int s = get_src(ei, md, e);
        int pos = atomicAdd(&cursor[d], 1);
        srcs[rows[d] + pos] = s;
    }
}

// ------- fused logits + softmax + aggregation: wave per node, 2 edges/wave --
// lanes 0-31 even edge slots, 32-63 odd; lane owns 8 channels as 4 float2 packs
// (pk_add/pk_max/pk_fma). 1-deep prefetch (R7-proven: TLP > ILP here).
// No online max: logits O(+-10), fp32 exp safe; normalization identical.
__global__ __launch_bounds__(256) void fused_agg_kernel(
        const ushort* __restrict__ xlb, const ushort* __restrict__ xrb,
        const float* __restrict__ att,
        const int* __restrict__ rows, const int* __restrict__ srcs,
        const float* __restrict__ bias, float* __restrict__ out) {
    const int lane = threadIdx.x & 63;
    const int n = (blockIdx.x * 256 + threadIdx.x) >> 6;
    if (n >= N_NODES) return;
    const int half = lane >> 5;       // edge-parity of this half-wave
    const int sl   = lane & 31;       // owns channels sl*8 .. sl*8+7
    const int start = rows[n], end = rows[n + 1];   // end > start (self loop)

    f32x2 xr2[4], at2[4];
    {
        uint4 c = *(const uint4*)(xrb + (size_t)n * HC + sl * 8);
        unsigned w[4] = {c.x, c.y, c.z, c.w};
#pragma unroll
        for (int j = 0; j < 4; ++j) {
            xr2[j][0] = __uint_as_float(w[j] << 16);
            xr2[j][1] = __uint_as_float(w[j] & 0xffff0000u);
        }
        float4 a0 = *(const float4*)&att[sl * 8];
        float4 a1 = *(const float4*)&att[sl * 8 + 4];
        at2[0][0] = a0.x; at2[0][1] = a0.y; at2[1][0] = a0.z; at2[1][1] = a0.w;
        at2[2][0] = a1.x; at2[2][1] = a1.y; at2[3][0] = a1.z; at2[3][1] = a1.w;
    }

    f32x2 acc2[4];
#pragma unroll
    for (int j = 0; j < 4; ++j) acc2[j] = (f32x2)0.f;
    float sm = 0.f;

    // 1-deep pipeline: next row in flight + next-next src id
    int i = start + half;
    uint4 rA = make_uint4(0, 0, 0, 0);
    int sB = -1;
    if (i < end) rA = *(const uint4*)(xlb + (size_t)srcs[i] * HC + sl * 8);
    if (i + 2 < end) sB = srcs[i + 2];

    for (; i < end; i += 2) {
        uint4 r = rA;
        if (sB >= 0) rA = *(const uint4*)(xlb + (size_t)sB * HC + sl * 8);
        sB = (i + 4 < end) ? srcs[i + 4] : -1;

        unsigned w[4] = {r.x, r.y, r.z, r.w};
        f32x2 xv[4];
#pragma unroll
        for (int j = 0; j < 4; ++j) {
            xv[j][0] = __uint_as_float(w[j] << 16);
            xv[j][1] = __uint_as_float(w[j] & 0xffff0000u);
        }

        f32x2 p2 = (f32x2)0.f;
#pragma unroll
        for (int j = 0; j < 4; ++j) {
            f32x2 v = xv[j] + xr2[j];                          // pk_add
            f32x2 lk = __builtin_elementwise_max(v, v * NEG);  // pk_mul + pk_max
            p2 = lk * at2[j] + p2;                             // pk_fma
        }
        float p = p2[0] + p2[1];
        p += __shfl_xor(p, 1, 64);
        p += __shfl_xor(p, 2, 64);
        p += __shfl_xor(p, 4, 64);

        float wgt = __expf(p);
        sm += wgt;
        f32x2 w2; w2[0] = wgt; w2[1] = wgt;
#pragma unroll
        for (int j = 0; j < 4; ++j) acc2[j] = xv[j] * w2 + acc2[j];  // pk_fma
    }

    // merge the two half-wave partials
    sm += __shfl_xor(sm, 32, 64);
#pragma unroll
    for (int j = 0; j < 4; ++j) {
        acc2[j][0] += __shfl_xor(acc2[j][0], 32, 64);
        acc2[j][1] += __shfl_xor(acc2[j][1], 32, 64);
    }

    if (half == 0) {
        const float inv = 1.0f / sm;
        float4 b0 = *(const float4*)&bias[sl * 8];
        float4 b1 = *(const float4*)&bias[sl * 8 + 4];
        float4 o0, o1;
        o0.x = fmaf(acc2[0][0], inv, b0.x); o0.y = fmaf(acc2[0][1], inv, b0.y);
        o0.z = fmaf(acc2[1][0], inv, b0.z); o0.w = fmaf(acc2[1][1], inv, b0.w);
        o1.x = fmaf(acc2[2][0], inv, b1.x); o1.y = fmaf(acc2[2][1], inv, b1.y);
        o1.z = fmaf(acc2[3][0], inv, b1.z); o1.w = fmaf(acc2[3][1], inv, b1.w);
        *(float4*)&out[(size_t)n * HC + sl * 8]     = o0;
        *(float4*)&out[(size_t)n * HC + sl * 8 + 4] = o1;
    }
}

// ---------------- host launcher ---------------------------------------------
extern "C" void kernel_launch(void* const* d_in, const int* in_sizes, int n_in,
                              void* d_out, int out_size, void* d_ws, size_t ws_size,
                              hipStream_t stream) {
    const float* x    = (const float*)d_in[0];
    const int*   ei   = (const int*)d_in[1];
    const float* Wl   = (const float*)d_in[2];
    const float* bl   = (const float*)d_in[3];
    const float* Wr   = (const float*)d_in[4];
    const float* br   = (const float*)d_in[5];
    const float* att  = (const float*)d_in[6];
    const float* bias = (const float*)d_in[7];
    float* out = (float*)d_out;

    char* ws = (char*)d_ws;
    int*   counts = (int*)(ws + OFF_COUNTS);
    int*   cursor = (int*)(ws + OFF_CUR);
    int*   rows   = (int*)(ws + OFF_ROWS);
    int*   srcs   = (int*)(ws + OFF_SRCS);
    int*   bsum   = (int*)(ws + OFF_BSUM);
    int*   mode   = (int*)(ws + OFF_MODE);
    ushort* xb    = (ushort*)(ws + OFF_XB);
    ushort* wt    = (ushort*)(ws + OFF_WT);
    ushort* xlb   = (ushort*)(ws + OFF_XLB);
    ushort* xrb   = (ushort*)(ws + OFF_XRB);

    // 1: fused cvt_x | cvt_w | zero(counts+cursor) | detect
    prep_kernel<<<XBLK + WBLK + ZBLK + 1, 256, 0, stream>>>(
        x, Wl, Wr, ei, xb, wt, counts, mode);

    // 2: MFMA GEMM blocks (XCD-swizzled) + count blocks at tail
    gemm_count_kernel<<<GEMM_BLKS + CNT_BLKS, 256, 0, stream>>>(
        (const __hip_bfloat16*)xb, (const __hip_bfloat16*)wt, bl, br, xlb, xrb,
        ei, mode, counts);

    // 3-4: scan
    scan1_kernel<<<49, 256, 0, stream>>>(counts, rows, bsum);
    scan3_kernel<<<(N_NODES + 255) / 256, 256, 0, stream>>>(rows, bsum);

    // 5: fill CSR with src ids
    fill_kernel<<<(E_TOT + 255) / 256, 256, 0, stream>>>(ei, mode, rows, cursor, srcs);

    // 6: fused attention + aggregation
    fused_agg_kernel<<<(N_NODES + 3) / 4, 256, 0, stream>>>(
        xlb, xrb, att, rows, srcs, bias, out);
}